// Round 1
// baseline (2592.238 us; speedup 1.0000x reference)
//
#include <hip/hip_runtime.h>
#include <hip/hip_bf16.h>

#define AS1 __attribute__((address_space(1)))
#define AS3 __attribute__((address_space(3)))

typedef __bf16 bf16x8 __attribute__((ext_vector_type(8)));
typedef float f32x4 __attribute__((ext_vector_type(4)));

static constexpr int C_DIM = 1024;
static constexpr int H_DIM = 4096;
static constexpr int NTOK = 8192;   // 4*2048
static constexpr int NR = 7;        // routed experts

static __device__ __forceinline__ unsigned short f2bf(float f) {
  __hip_bfloat16 h = __float2bfloat16(f);
  return *reinterpret_cast<unsigned short*>(&h);
}

static __device__ __forceinline__ void gload16(const void* g, void* lds) {
  __builtin_amdgcn_global_load_lds((const AS1 void*)g, (AS3 void*)lds, 16, 0, 0);
}

// ---------------- cast x (fp32 -> bf16), 4 elems/thread ----------------
__global__ __launch_bounds__(256) void cast_x_kernel(const float* __restrict__ x,
                                                     unsigned short* __restrict__ xb) {
  size_t i = ((size_t)blockIdx.x * blockDim.x + threadIdx.x) * 4;
  float4 v = *(const float4*)(x + i);
  ushort4 o;
  o.x = f2bf(v.x); o.y = f2bf(v.y); o.z = f2bf(v.z); o.w = f2bf(v.w);
  *(ushort4*)(xb + i) = o;
}

// ---------------- routing: one wave per token ----------------
__global__ __launch_bounds__(256) void routing_kernel(const float* __restrict__ x,
                                                      const float* __restrict__ gw,
                                                      const float* __restrict__ bias,
                                                      float* __restrict__ cw) {
  int wid = (int)((blockIdx.x * (size_t)blockDim.x + threadIdx.x) >> 6);
  int lane = threadIdx.x & 63;
  if (wid >= NTOK) return;
  const float* xt = x + (size_t)wid * C_DIM;
  float p[NR] = {0.f, 0.f, 0.f, 0.f, 0.f, 0.f, 0.f};
  for (int i = lane; i < C_DIM; i += 64) {
    float xv = xt[i];
#pragma unroll
    for (int e = 0; e < NR; ++e) p[e] += xv * gw[e * C_DIM + i];
  }
#pragma unroll
  for (int e = 0; e < NR; ++e) {
#pragma unroll
    for (int off = 32; off; off >>= 1) p[e] += __shfl_down(p[e], off);
  }
  if (lane == 0) {
    float m = p[0];
#pragma unroll
    for (int e = 1; e < NR; ++e) m = fmaxf(m, p[e]);
    float pr[NR], s = 0.f;
#pragma unroll
    for (int e = 0; e < NR; ++e) { pr[e] = __expf(p[e] - m); s += pr[e]; }
    float inv = 1.0f / s;
#pragma unroll
    for (int e = 0; e < NR; ++e) pr[e] *= inv;
    float sel[NR];
#pragma unroll
    for (int e = 0; e < NR; ++e) sel[e] = p[e] + bias[e];
    int i1 = 0;
#pragma unroll
    for (int e = 1; e < NR; ++e) if (sel[e] > sel[i1]) i1 = e;
    int i2 = -1;
#pragma unroll
    for (int e = 0; e < NR; ++e) {
      if (e == i1) continue;
      if (i2 < 0 || sel[e] > sel[i2]) i2 = e;
    }
    float c[NR] = {0.f, 0.f, 0.f, 0.f, 0.f, 0.f, 0.f};
    c[i1] = pr[i1];
    c[i2] += pr[i2];
#pragma unroll
    for (int e = 0; e < NR; ++e) cw[(size_t)wid * NR + e] = c[e];
  }
}

// ---------------- transpose + cast: in fp32 [R][S] -> out bf16 [S][R] ----------------
__global__ void transpose_cast(const float* __restrict__ in, unsigned short* __restrict__ out,
                               int R, int S) {
  __shared__ float t[32][33];
  int bx = blockIdx.x * 32;  // S
  int by = blockIdx.y * 32;  // R
  int tx = threadIdx.x, ty = threadIdx.y;  // (32, 8)
#pragma unroll
  for (int i = 0; i < 32; i += 8)
    t[ty + i][tx] = in[(size_t)(by + ty + i) * S + bx + tx];
  __syncthreads();
#pragma unroll
  for (int i = 0; i < 32; i += 8)
    out[(size_t)(bx + ty + i) * R + by + tx] = f2bf(t[tx][ty + i]);
}

// ---------------- 128x128 tile GEMM, A [M][K] bf16, Bt [N][K] bf16 ----------------
// EPI 0: Y[row*Nld+col] = bf16(gelu_exact(v))
// EPI 1: Out[row*Nld+col] = v            (shared expert, initializes out)
// EPI 2: Out[row*Nld+col] += cw[row*7+eidx] * v
template <int EPI>
__global__ __launch_bounds__(256) void gemm128(const unsigned short* __restrict__ A,
                                               const unsigned short* __restrict__ Bt,
                                               int K,
                                               unsigned short* __restrict__ Y,
                                               float* __restrict__ Out,
                                               const float* __restrict__ cw,
                                               int eidx, int Nld) {
  // LDS layout: [kg=4][row=128][8 bf16] per matrix -> conflict-free ds_read_b128
  __shared__ __align__(16) unsigned short As[4 * 128 * 8];
  __shared__ __align__(16) unsigned short Bs[4 * 128 * 8];

  const int tid = threadIdx.x;
  const int wave = tid >> 6, lane = tid & 63;
  const int m0 = blockIdx.y * 128, n0 = blockIdx.x * 128;
  const int wr = wave >> 1, wc = wave & 1;   // 2x2 wave grid, each 64x64
  const int fr = lane & 15, fq = lane >> 4;

  f32x4 acc[4][4] = {};

  for (int k0 = 0; k0 < K; k0 += 32) {
#pragma unroll
    for (int t = 0; t < 2; ++t) {
      const int c = wave * 2 + t;          // wave-uniform chunk group
      const int q = c * 64 + lane;         // 16B chunk index 0..511
      const int kg = q >> 7, r = q & 127;  // LDS chunk q <-> (kg, row)
      gload16(A + (size_t)(m0 + r) * K + k0 + kg * 8, &As[c * 512]);
      gload16(Bt + (size_t)(n0 + r) * K + k0 + kg * 8, &Bs[c * 512]);
    }
    __syncthreads();  // drains vmcnt before barrier

    bf16x8 af[4], bf[4];
#pragma unroll
    for (int m = 0; m < 4; ++m)
      af[m] = *(const bf16x8*)&As[fq * 1024 + (wr * 64 + m * 16 + fr) * 8];
#pragma unroll
    for (int n = 0; n < 4; ++n)
      bf[n] = *(const bf16x8*)&Bs[fq * 1024 + (wc * 64 + n * 16 + fr) * 8];
#pragma unroll
    for (int m = 0; m < 4; ++m)
#pragma unroll
      for (int n = 0; n < 4; ++n)
        acc[m][n] = __builtin_amdgcn_mfma_f32_16x16x32_bf16(af[m], bf[n], acc[m][n], 0, 0, 0);
    __syncthreads();
  }

#pragma unroll
  for (int m = 0; m < 4; ++m) {
#pragma unroll
    for (int n = 0; n < 4; ++n) {
#pragma unroll
      for (int j = 0; j < 4; ++j) {
        const int row = m0 + wr * 64 + m * 16 + fq * 4 + j;
        const int col = n0 + wc * 64 + n * 16 + fr;
        const float v = acc[m][n][j];
        if (EPI == 0) {
          const float g = 0.5f * v * (1.0f + erff(v * 0.70710678118654752f));
          Y[(size_t)row * Nld + col] = f2bf(g);
        } else if (EPI == 1) {
          Out[(size_t)row * Nld + col] = v;
        } else {
          const float s = cw[(size_t)row * NR + eidx];
          if (s != 0.0f) Out[(size_t)row * Nld + col] += s * v;
        }
      }
    }
  }
}

extern "C" void kernel_launch(void* const* d_in, const int* in_sizes, int n_in,
                              void* d_out, int out_size, void* d_ws, size_t ws_size,
                              hipStream_t stream) {
  const float* x            = (const float*)d_in[0];
  const float* gate_w       = (const float*)d_in[1];
  const float* lb_bias      = (const float*)d_in[2];
  const float* shared_wfc   = (const float*)d_in[3];
  const float* shared_wproj = (const float*)d_in[4];
  const float* routed_wfc   = (const float*)d_in[5];
  const float* routed_wproj = (const float*)d_in[6];
  float* out = (float*)d_out;

  char* ws = (char*)d_ws;
  unsigned short* xb     = (unsigned short*)(ws);                 // 16 MiB
  float*          cw     = (float*)(ws + 16777216);               // 224 KiB
  unsigned short* wfcT   = (unsigned short*)(ws + 17006592);      // 8 MiB  [H][C]
  unsigned short* wprojT = (unsigned short*)(ws + 25395200);      // 8 MiB  [C][H]
  unsigned short* Yb     = (unsigned short*)(ws + 33783808);      // 64 MiB [NTOK][H]

  cast_x_kernel<<<NTOK * C_DIM / (256 * 4), 256, 0, stream>>>(x, xb);
  routing_kernel<<<NTOK / 4, 256, 0, stream>>>(x, gate_w, lb_bias, cw);

  for (int e = 0; e < 8; ++e) {
    const float* wfc   = (e == 0) ? shared_wfc   : routed_wfc   + (size_t)(e - 1) * C_DIM * H_DIM;
    const float* wproj = (e == 0) ? shared_wproj : routed_wproj + (size_t)(e - 1) * H_DIM * C_DIM;
    // wfc [C][H] -> wfcT [H][C];  wproj [H][C] -> wprojT [C][H]
    transpose_cast<<<dim3(H_DIM / 32, C_DIM / 32), dim3(32, 8), 0, stream>>>(wfc, wfcT, C_DIM, H_DIM);
    transpose_cast<<<dim3(C_DIM / 32, H_DIM / 32), dim3(32, 8), 0, stream>>>(wproj, wprojT, H_DIM, C_DIM);

    // fc: [NTOK,C] x [C,H] -> Y (gelu, bf16)
    gemm128<0><<<dim3(H_DIM / 128, NTOK / 128), 256, 0, stream>>>(
        xb, wfcT, C_DIM, Yb, nullptr, nullptr, 0, H_DIM);
    // proj: [NTOK,H] x [H,C] -> out (fp32)
    if (e == 0)
      gemm128<1><<<dim3(C_DIM / 128, NTOK / 128), 256, 0, stream>>>(
          Yb, wprojT, H_DIM, nullptr, out, nullptr, 0, C_DIM);
    else
      gemm128<2><<<dim3(C_DIM / 128, NTOK / 128), 256, 0, stream>>>(
          Yb, wprojT, H_DIM, nullptr, out, cw, e - 1, C_DIM);
  }
}